// Round 1
// baseline (181.144 us; speedup 1.0000x reference)
//
#include <hip/hip_runtime.h>

// Segment-mean of subtoken embeddings (sorted segment ids) -> token embeddings.
// One block per (b, t) output row; 192 threads x float4 = 768 floats (D).
// Binary search finds the contiguous subtoken range [lo, hi) for token t.

__global__ void __launch_bounds__(192) seg_mean_kernel(
    const float* __restrict__ hs,      // [B, S, D] f32
    const int* __restrict__ seg,       // [B, S] sorted per row
    const int* __restrict__ num_tokens_p,
    float* __restrict__ out,           // [B, T, D]
    int BS_total,                      // B*S
    int D) {
  const int T = num_tokens_p[0];           // uniform scalar load
  const int BT = gridDim.x;                // B*T
  const int S = (int)(((long long)BS_total * T) / BT);  // exact
  const int b = blockIdx.x / T;
  const int t = blockIdx.x - b * T;

  const int* __restrict__ row = seg + (size_t)b * S;

  // lower_bound(t): first index with row[i] >= t
  int lo = 0, n = S;
  while (n > 0) {
    int half = n >> 1;
    int mid = lo + half;
    if (row[mid] < t) { lo = mid + 1; n -= half + 1; } else { n = half; }
  }
  // lower_bound(t+1) starting from lo
  int hi = lo; n = S - lo;
  while (n > 0) {
    int half = n >> 1;
    int mid = hi + half;
    if (row[mid] < t + 1) { hi = mid + 1; n -= half + 1; } else { n = half; }
  }
  const int cnt = hi - lo;

  const int d4 = threadIdx.x;        // [0, D/4)
  const int rowstride4 = D >> 2;

  const float4* __restrict__ p =
      (const float4*)(hs + ((size_t)b * S + lo) * D) + d4;

  float4 acc = make_float4(0.f, 0.f, 0.f, 0.f);
  for (int s = 0; s < cnt; ++s) {
    float4 v = p[(size_t)s * rowstride4];
    acc.x += v.x; acc.y += v.y; acc.z += v.z; acc.w += v.w;
  }

  const float inv = (cnt > 0) ? (1.0f / (float)cnt) : 0.0f;
  float4 o = make_float4(acc.x * inv, acc.y * inv, acc.z * inv, acc.w * inv);

  ((float4*)(out + (size_t)blockIdx.x * D))[d4] = o;
}

extern "C" void kernel_launch(void* const* d_in, const int* in_sizes, int n_in,
                              void* d_out, int out_size, void* d_ws, size_t ws_size,
                              hipStream_t stream) {
  const float* hs = (const float*)d_in[0];
  const int* seg = (const int*)d_in[1];
  const int* num_tokens_p = (const int*)d_in[2];
  float* out = (float*)d_out;

  const int BS_total = in_sizes[1];                  // B*S
  const int D = in_sizes[0] / in_sizes[1];           // 768
  const int BT = out_size / D;                       // B*T

  dim3 grid(BT);
  dim3 block(D / 4);                                 // 192 threads
  hipLaunchKernelGGL(seg_mean_kernel, grid, block, 0, stream,
                     hs, seg, num_tokens_p, out, BS_total, D);
}

// Round 2
// 174.749 us; speedup vs baseline: 1.0366x; 1.0366x over previous
//
#include <hip/hip_runtime.h>

// Segment-mean of subtoken embeddings (sorted segment ids) -> token embeddings.
//
// Phase 1 (bounds_kernel): build lower_bound table start[b][t] = first s with
//   seg[b,s] >= t, for t in [0, T]; start[b][T] = S. Each entry written exactly
//   once (thread s owns t in (seg[s-1], seg[s]]). Removes the dependent
//   binary-search chain (~36 x 200cyc) that made round 1 latency-bound.
// Phase 2 (seg_mean_kernel): one block per (b,t) row; 2 uniform loads give
//   [lo,hi), then stream cnt rows (float4, coalesced) and write the mean.

__global__ void bounds_kernel(const int* __restrict__ seg,
                              const int* __restrict__ num_tokens_p,
                              int* __restrict__ start,
                              int BS_total,   // B*S
                              int BT) {       // B*T
  const int T = num_tokens_p[0];
  const int B = BT / T;
  const int S = BS_total / B;
  int idx = blockIdx.x * blockDim.x + threadIdx.x;
  if (idx >= BS_total) return;
  const int b = idx / S;
  const int s = idx - b * S;
  const int cur = seg[idx];
  const int prev = (s == 0) ? -1 : seg[idx - 1];
  int* __restrict__ row = start + (size_t)b * (T + 1);
  for (int t = prev + 1; t <= cur; ++t) row[t] = s;
  if (s == S - 1) {
    for (int t = cur + 1; t <= T; ++t) row[t] = S;
  }
}

__global__ void __launch_bounds__(192) seg_mean_kernel(
    const float* __restrict__ hs,      // [B, S, D] f32
    const int* __restrict__ start,     // [B, T+1]
    const int* __restrict__ num_tokens_p,
    float* __restrict__ out,           // [B, T, D]
    int BS_total,
    int D) {
  const int T = num_tokens_p[0];
  const int BT = gridDim.x;
  const int S = (int)(((long long)BS_total * T) / BT);
  const int b = blockIdx.x / T;
  const int t = blockIdx.x - b * T;

  const int* __restrict__ srow = start + (size_t)b * (T + 1) + t;
  const int lo = srow[0];
  const int hi = srow[1];
  const int cnt = hi - lo;

  const int d4 = threadIdx.x;        // [0, D/4)
  const int rowstride4 = D >> 2;

  const float4* __restrict__ p =
      (const float4*)(hs + ((size_t)b * S + lo) * D) + d4;

  float4 acc = make_float4(0.f, 0.f, 0.f, 0.f);
  for (int s = 0; s < cnt; ++s) {
    float4 v = p[(size_t)s * rowstride4];
    acc.x += v.x; acc.y += v.y; acc.z += v.z; acc.w += v.w;
  }

  const float inv = (cnt > 0) ? (1.0f / (float)cnt) : 0.0f;
  float4 o = make_float4(acc.x * inv, acc.y * inv, acc.z * inv, acc.w * inv);

  ((float4*)(out + (size_t)blockIdx.x * D))[d4] = o;
}

// Fallback (round-1): per-block binary search, used only if d_ws is too small.
__global__ void __launch_bounds__(192) seg_mean_search_kernel(
    const float* __restrict__ hs,
    const int* __restrict__ seg,
    const int* __restrict__ num_tokens_p,
    float* __restrict__ out,
    int BS_total,
    int D) {
  const int T = num_tokens_p[0];
  const int BT = gridDim.x;
  const int S = (int)(((long long)BS_total * T) / BT);
  const int b = blockIdx.x / T;
  const int t = blockIdx.x - b * T;
  const int* __restrict__ row = seg + (size_t)b * S;

  int lo = 0, n = S;
  while (n > 0) {
    int half = n >> 1;
    int mid = lo + half;
    if (row[mid] < t) { lo = mid + 1; n -= half + 1; } else { n = half; }
  }
  int hi = lo; n = S - lo;
  while (n > 0) {
    int half = n >> 1;
    int mid = hi + half;
    if (row[mid] < t + 1) { hi = mid + 1; n -= half + 1; } else { n = half; }
  }
  const int cnt = hi - lo;

  const int d4 = threadIdx.x;
  const int rowstride4 = D >> 2;
  const float4* __restrict__ p =
      (const float4*)(hs + ((size_t)b * S + lo) * D) + d4;

  float4 acc = make_float4(0.f, 0.f, 0.f, 0.f);
  for (int s = 0; s < cnt; ++s) {
    float4 v = p[(size_t)s * rowstride4];
    acc.x += v.x; acc.y += v.y; acc.z += v.z; acc.w += v.w;
  }
  const float inv = (cnt > 0) ? (1.0f / (float)cnt) : 0.0f;
  float4 o = make_float4(acc.x * inv, acc.y * inv, acc.z * inv, acc.w * inv);
  ((float4*)(out + (size_t)blockIdx.x * D))[d4] = o;
}

extern "C" void kernel_launch(void* const* d_in, const int* in_sizes, int n_in,
                              void* d_out, int out_size, void* d_ws, size_t ws_size,
                              hipStream_t stream) {
  const float* hs = (const float*)d_in[0];
  const int* seg = (const int*)d_in[1];
  const int* num_tokens_p = (const int*)d_in[2];
  float* out = (float*)d_out;

  const int BS_total = in_sizes[1];                  // B*S
  const int D = in_sizes[0] / in_sizes[1];           // 768
  const int BT = out_size / D;                       // B*T

  // start table needs B*(T+1) ints; B <= BT, so 4*(BT + BT) is a safe bound,
  // and 4*(BT + BS_total) is even safer (B <= min(BT, BS_total)).
  const size_t ws_needed = (size_t)4 * ((size_t)BT + (size_t)BS_total);

  if (ws_size >= ws_needed) {
    int* start = (int*)d_ws;
    const int threads1 = 256;
    const int grid1 = (BS_total + threads1 - 1) / threads1;
    hipLaunchKernelGGL(bounds_kernel, dim3(grid1), dim3(threads1), 0, stream,
                       seg, num_tokens_p, start, BS_total, BT);
    hipLaunchKernelGGL(seg_mean_kernel, dim3(BT), dim3(D / 4), 0, stream,
                       hs, start, num_tokens_p, out, BS_total, D);
  } else {
    hipLaunchKernelGGL(seg_mean_search_kernel, dim3(BT), dim3(D / 4), 0, stream,
                       hs, seg, num_tokens_p, out, BS_total, D);
  }
}